// Round 1
// baseline (591.441 us; speedup 1.0000x reference)
//
#include <hip/hip_runtime.h>
#include <hip/hip_bf16.h>

typedef __attribute__((ext_vector_type(8))) __bf16 bf16x8;
typedef __attribute__((ext_vector_type(4))) __bf16 bf16x4;
typedef __attribute__((ext_vector_type(4))) float f32x4;

#define MFMA16(a, b, c) __builtin_amdgcn_mfma_f32_16x16x32_bf16((a), (b), (c), 0, 0, 0)

__device__ __forceinline__ void gload_lds16(const void* g, void* l) {
    __builtin_amdgcn_global_load_lds((const __attribute__((address_space(1))) void*)g,
                                     (__attribute__((address_space(3))) void*)l, 16, 0, 0);
}

// ---------------- f32 -> bf16 convert (x) ----------------
__global__ __launch_bounds__(256) void cvt_bf16(const float* __restrict__ in,
                                                __bf16* __restrict__ out, int n4) {
    int i = blockIdx.x * 256 + threadIdx.x;
    if (i >= n4) return;
    f32x4 v = *(const f32x4*)(in + (size_t)i * 4);
    bf16x4 o;
#pragma unroll
    for (int j = 0; j < 4; j++) o[j] = (__bf16)v[j];
    *(bf16x4*)(out + (size_t)i * 4) = o;
}

// ---------------- weight transpose f32 (R,C) -> bf16 (C,R) ----------------
__global__ __launch_bounds__(256) void transpose_w(const float* __restrict__ in,
                                                   __bf16* __restrict__ out, int R, int C) {
    __shared__ float tile[32][33];
    const int c0 = blockIdx.x * 32, r0 = blockIdx.y * 32;
    const int tx = threadIdx.x, ty = threadIdx.y;
#pragma unroll
    for (int k = 0; k < 32; k += 8)
        tile[ty + k][tx] = in[(size_t)(r0 + ty + k) * C + c0 + tx];
    __syncthreads();
#pragma unroll
    for (int k = 0; k < 32; k += 8)
        out[(size_t)(c0 + ty + k) * R + r0 + tx] = (__bf16)tile[tx][ty + k];
}

// ---------------- GEMM: C(M,N) = A(M,K)bf16 @ Bt(N,K)bf16^T  (m97 structure) ----------------
template <typename OUT_T>
__global__ __launch_bounds__(256) void gemm_bt(const __bf16* __restrict__ A,
                                               const __bf16* __restrict__ Bt,
                                               OUT_T* __restrict__ C, int M, int N, int K) {
    __shared__ alignas(16) __bf16 As[4096];
    __shared__ alignas(16) __bf16 Bs[4096];
    const int tid = threadIdx.x;
    const int wv = tid >> 6;
    const int nwg = gridDim.x;
    const int cpx = nwg >> 3;
    const int bid = blockIdx.x;
    const int wg = (bid & 7) * cpx + (bid >> 3);  // XCD swizzle (nwg % 8 == 0 in all launches)
    const int nbn = N >> 7;
    const int bm = wg / nbn, bn = wg - bm * nbn;

    const __bf16* Ab = A + (size_t)bm * 128 * K;
    const __bf16* Bb = Bt + (size_t)bn * 128 * K;
    const int srow = tid >> 2;
    const int skc = (tid & 3) * 8;
    const int lr = tid & 15;
    const int lk = ((tid >> 4) & 3) * 8;
    const int wm = (wv >> 1) * 64, wn = (wv & 1) * 64;

    f32x4 acc[4][4] = {};
    for (int kt = 0; kt < K; kt += 32) {
        gload_lds16(Ab + (size_t)srow * K + kt + skc, As + wv * 512);
        gload_lds16(Ab + (size_t)(srow + 64) * K + kt + skc, As + 2048 + wv * 512);
        gload_lds16(Bb + (size_t)srow * K + kt + skc, Bs + wv * 512);
        gload_lds16(Bb + (size_t)(srow + 64) * K + kt + skc, Bs + 2048 + wv * 512);
        asm volatile("s_waitcnt vmcnt(0)" ::: "memory");
        __syncthreads();
        bf16x8 af[4], bfr[4];
#pragma unroll
        for (int i = 0; i < 4; i++) af[i] = *(const bf16x8*)(As + (wm + i * 16 + lr) * 32 + lk);
#pragma unroll
        for (int j = 0; j < 4; j++) bfr[j] = *(const bf16x8*)(Bs + (wn + j * 16 + lr) * 32 + lk);
#pragma unroll
        for (int i = 0; i < 4; i++)
#pragma unroll
            for (int j = 0; j < 4; j++) acc[i][j] = MFMA16(af[i], bfr[j], acc[i][j]);
        __syncthreads();
    }
    const int lro = ((tid >> 4) & 3) * 4;
#pragma unroll
    for (int i = 0; i < 4; i++)
#pragma unroll
        for (int j = 0; j < 4; j++) {
            size_t base = (size_t)(bm * 128 + wm + i * 16 + lro) * N + bn * 128 + wn + j * 16 + lr;
#pragma unroll
            for (int r = 0; r < 4; r++) C[base + (size_t)r * N] = (OUT_T)acc[i][j][r];
        }
}

// ---------------- t = x @ gk_w1  (8192x16) ----------------
__global__ __launch_bounds__(256) void gk1_proj(const float* __restrict__ x,
                                                const float* __restrict__ w1,
                                                float* __restrict__ t) {
    const int row = blockIdx.x * 4 + (threadIdx.x >> 6);
    const int l = threadIdx.x & 63;
    const int r = l & 15, kg = l >> 4;
    const float* xr = x + (size_t)row * 1024;
    const float* w1p = w1 + r;
    float acc = 0.f;
    for (int k = kg * 256; k < (kg + 1) * 256; ++k) acc = fmaf(xr[k], w1p[k * 16], acc);
    acc += __shfl_xor(acc, 16);
    acc += __shfl_xor(acc, 32);
    if (kg == 0) t[(size_t)row * 16 + r] = acc;
}

// ---------------- per-(b,h,chunk): gates, qg/kg/kH, A=qg kg^T (causal), o_intra = A v ----------------
__global__ __launch_bounds__(256) void chunk_pre(
    const float* __restrict__ tbuf,   // (8192,16)
    const float* __restrict__ w2,     // (16,1024)
    const float* __restrict__ b2,     // (1024)
    const __bf16* __restrict__ qkg,   // (8192,4096): q|k|g
    const __bf16* __restrict__ vt,    // (2048,8192)
    __bf16* __restrict__ qg,          // (8192,1024)
    __bf16* __restrict__ kHt,         // (16,256,2048)
    float* __restrict__ eblast,       // (32,16,256)
    __bf16* __restrict__ o)           // (8192,2048)
{
    __shared__ float t_l[64 * 16];
    __shared__ float Bc[64 * 258];
    __shared__ alignas(16) __bf16 qg_l[64 * 264];
    __shared__ alignas(16) __bf16 kg_l[64 * 264];
    __shared__ alignas(16) __bf16 A_l[64 * 72];

    const int bid = blockIdx.x;  // (b*4+h)*32 + nc
    const int nc = bid & 31;
    const int bh = bid >> 5;
    const int b = bh >> 2, h = bh & 3;
    const int tid = threadIdx.x;
    const int seq0 = b * 2048 + nc * 64;
    const int d = tid;
    const int hd = h * 256 + d;

    for (int i = tid; i < 64 * 16; i += 256) t_l[i] = tbuf[(size_t)seq0 * 16 + i];
    float w2c[16];
#pragma unroll
    for (int r = 0; r < 16; r++) w2c[r] = w2[r * 1024 + hd];
    const float b2v = b2[hd];
    __syncthreads();

    // pass1: inclusive cumsum of gk over chunk positions (column d owned by this thread)
    float bsum = 0.f;
    for (int c = 0; c < 64; c++) {
        float u = b2v;
#pragma unroll
        for (int r = 0; r < 16; r++) u += t_l[c * 16 + r] * w2c[r];
        float ls = fminf(u, 0.f) - log1pf(expf(-fabsf(u)));  // log_sigmoid
        bsum += ls * 0.0625f;                                // / GATE_NORM
        Bc[c * 258 + d] = bsum;
    }
    const float blast = bsum;
    eblast[(size_t)(nc * 16 + bh) * 256 + d] = expf(blast);

    // pass2: qg, kg, kH (kH overwrites Bc slot after read; same-thread only)
    for (int c = 0; c < 64; c++) {
        float bc = Bc[c * 258 + d];
        float qv = (float)qkg[(size_t)(seq0 + c) * 4096 + hd];
        float kv = (float)qkg[(size_t)(seq0 + c) * 4096 + 1024 + hd];
        float qgv = qv * expf(bc) * 0.0625f;  // scale = dk^-0.5 = 1/16
        float kgv = kv * expf(-bc);
        float kHv = kv * expf(blast - bc);
        qg[(size_t)(seq0 + c) * 1024 + hd] = (__bf16)qgv;
        qg_l[c * 264 + d] = (__bf16)qgv;
        kg_l[c * 264 + d] = (__bf16)kgv;
        Bc[c * 258 + d] = kHv;
    }
    __syncthreads();

    // pass3: write kHt transposed (d-major, c-contiguous)
    {
        const int c = tid & 63;
        const int dq = tid >> 6;
        for (int i = 0; i < 64; i++) {
            int dd = i * 4 + dq;
            kHt[(size_t)(bh * 256 + dd) * 2048 + nc * 64 + c] = (__bf16)Bc[c * 258 + dd];
        }
    }

    const int wv = tid >> 6, l = tid & 63;
    const int lr = l & 15, lk = (l >> 4) * 8, lro = (l >> 4) * 4;

    // pass4: A = qg @ kg^T (64x64, K=256), causal mask, store bf16
    {
        f32x4 acc[4] = {};
#pragma unroll
        for (int ks = 0; ks < 8; ks++) {
            bf16x8 a = *(const bf16x8*)(qg_l + (wv * 16 + lr) * 264 + ks * 32 + lk);
#pragma unroll
            for (int sf = 0; sf < 4; sf++) {
                bf16x8 bb = *(const bf16x8*)(kg_l + (sf * 16 + lr) * 264 + ks * 32 + lk);
                acc[sf] = MFMA16(a, bb, acc[sf]);
            }
        }
#pragma unroll
        for (int sf = 0; sf < 4; sf++)
#pragma unroll
            for (int r = 0; r < 4; r++) {
                int tt = wv * 16 + lro + r;
                int ss = sf * 16 + lr;
                A_l[tt * 72 + ss] = (ss <= tt) ? (__bf16)acc[sf][r] : (__bf16)0.f;
            }
    }
    __syncthreads();

    // pass5: o_intra = A @ v  (64 x 512), B-operand from vt (K-contiguous)
    {
        f32x4 acc[4][8] = {};
        const __bf16* vbase = vt + (size_t)(h * 512 + wv * 128) * 8192 + b * 2048 + nc * 64;
#pragma unroll
        for (int ks = 0; ks < 2; ks++) {
            bf16x8 a[4];
#pragma unroll
            for (int rf = 0; rf < 4; rf++)
                a[rf] = *(const bf16x8*)(A_l + (rf * 16 + lr) * 72 + ks * 32 + lk);
#pragma unroll
            for (int cf = 0; cf < 8; cf++) {
                bf16x8 bb = *(const bf16x8*)(vbase + (size_t)(cf * 16 + lr) * 8192 + ks * 32 + lk);
#pragma unroll
                for (int rf = 0; rf < 4; rf++) acc[rf][cf] = MFMA16(a[rf], bb, acc[rf][cf]);
            }
        }
#pragma unroll
        for (int rf = 0; rf < 4; rf++)
#pragma unroll
            for (int cf = 0; cf < 8; cf++)
#pragma unroll
                for (int r = 0; r < 4; r++)
                    o[(size_t)(seq0 + rf * 16 + lro + r) * 2048 + h * 512 + wv * 128 + cf * 16 + lr] =
                        (__bf16)acc[rf][cf][r];
    }
}

// ---------------- sequential chunk scan: o += qg @ H^T ; H = diag(e^blast) H + kH^T v ----------------
// grid: (b,h,es) = 128 blocks, 512 threads. Waves 0-3: o_inter; waves 4-7: H-update MFMA (concurrent).
__global__ __launch_bounds__(512) void scan_kernel(
    const __bf16* __restrict__ qg, const __bf16* __restrict__ kHt,
    const __bf16* __restrict__ vt, const float* __restrict__ eblast,
    __bf16* __restrict__ o) {
    __shared__ alignas(16) __bf16 Ht_l[64 * 264];  // [e][d], padded
    const int bid = blockIdx.x;
    const int es = bid & 7, bh = bid >> 3;
    const int b = bh >> 2, h = bh & 3;
    const int tid = threadIdx.x, wv = tid >> 6, l = tid & 63;
    const int lr = l & 15, lk = (l >> 4) * 8, lro = (l >> 4) * 4;
    for (int i = tid; i < 64 * 264; i += 512) Ht_l[i] = (__bf16)0.f;
    __syncthreads();
    const int ocol0 = h * 512 + es * 64;
    for (int nc = 0; nc < 32; nc++) {
        const int seq0 = b * 2048 + nc * 64;
        f32x4 acc2[16] = {};
        if (wv < 4) {
            // o_inter rows wv*16..+15, all 64 e of this slice
            f32x4 acc[4] = {};
            const __bf16* qrow = qg + (size_t)(seq0 + wv * 16 + lr) * 1024 + h * 256;
#pragma unroll
            for (int ks = 0; ks < 8; ks++) {
                bf16x8 a = *(const bf16x8*)(qrow + ks * 32 + lk);
#pragma unroll
                for (int cf = 0; cf < 4; cf++) {
                    bf16x8 bb = *(const bf16x8*)(Ht_l + (cf * 16 + lr) * 264 + ks * 32 + lk);
                    acc[cf] = MFMA16(a, bb, acc[cf]);
                }
            }
#pragma unroll
            for (int cf = 0; cf < 4; cf++)
#pragma unroll
                for (int r = 0; r < 4; r++) {
                    size_t oi = (size_t)(seq0 + wv * 16 + lro + r) * 2048 + ocol0 + cf * 16 + lr;
                    o[oi] = (__bf16)((float)o[oi] + acc[cf][r]);
                }
        } else {
            const int wh = wv - 4;
            const __bf16* va = vt + (size_t)(h * 512 + es * 64 + wh * 16 + lr) * 8192 + b * 2048 + nc * 64;
            const __bf16* kb = kHt + (size_t)bh * 256 * 2048 + nc * 64;
#pragma unroll
            for (int ks = 0; ks < 2; ks++) {
                bf16x8 a = *(const bf16x8*)(va + ks * 32 + lk);
#pragma unroll
                for (int cf = 0; cf < 16; cf++) {
                    bf16x8 bb = *(const bf16x8*)(kb + (size_t)(cf * 16 + lr) * 2048 + ks * 32 + lk);
                    acc2[cf] = MFMA16(a, bb, acc2[cf]);
                }
            }
        }
        __syncthreads();  // all o_inter reads of Ht_l complete
        if (wv >= 4) {
            const int wh = wv - 4;
            const float* ebl = eblast + (size_t)(nc * 16 + bh) * 256;
#pragma unroll
            for (int cf = 0; cf < 16; cf++) {
                const float e = ebl[cf * 16 + lr];
#pragma unroll
                for (int r = 0; r < 4; r++) {
                    const int ii = (wh * 16 + lro + r) * 264 + cf * 16 + lr;
                    Ht_l[ii] = (__bf16)(e * (float)Ht_l[ii] + acc2[cf][r]);
                }
            }
        }
        __syncthreads();
    }
}

// ---------------- RMS norm over dv=512 + SiLU gating ----------------
__global__ __launch_bounds__(256) void rms_gate(const __bf16* __restrict__ o,
                                                const __bf16* __restrict__ qkg,
                                                const float* __restrict__ gnw,
                                                __bf16* __restrict__ gated) {
    const int idx = blockIdx.x * 4 + (threadIdx.x >> 6);
    const int seq = idx >> 2, h = idx & 3;
    const int l = threadIdx.x & 63;
    bf16x8 ov = *(const bf16x8*)(o + (size_t)seq * 2048 + h * 512 + l * 8);
    float v[8];
    float ms = 0.f;
#pragma unroll
    for (int j = 0; j < 8; j++) {
        v[j] = (float)ov[j];
        ms += v[j] * v[j];
    }
#pragma unroll
    for (int off = 1; off < 64; off <<= 1) ms += __shfl_xor(ms, off);
    const float rinv = rsqrtf(ms * (1.f / 512.f) + 1e-5f);
    bf16x8 gv = *(const bf16x8*)(qkg + (size_t)seq * 4096 + 2048 + h * 512 + l * 8);
    const float* gw = gnw + l * 8;
    bf16x8 outv;
#pragma unroll
    for (int j = 0; j < 8; j++) {
        float g = (float)gv[j];
        float sig = 1.f / (1.f + expf(-g));
        outv[j] = (__bf16)(v[j] * rinv * gw[j] * g * sig);
    }
    *(bf16x8*)(gated + (size_t)seq * 2048 + h * 512 + l * 8) = outv;
}

extern "C" void kernel_launch(void* const* d_in, const int* in_sizes, int n_in,
                              void* d_out, int out_size, void* d_ws, size_t ws_size,
                              hipStream_t stream) {
    const float* x = (const float*)d_in[0];
    const float* Wq = (const float*)d_in[1];
    const float* Wk = (const float*)d_in[2];
    const float* Wv = (const float*)d_in[3];
    const float* Wg = (const float*)d_in[4];
    const float* w1 = (const float*)d_in[5];
    const float* w2 = (const float*)d_in[6];
    const float* b2 = (const float*)d_in[7];
    const float* gnw = (const float*)d_in[8];
    const float* Wo = (const float*)d_in[9];
    float* out = (float*)d_out;

    char* p = (char*)d_ws;
    auto nxt = [&](size_t bytes) {
        char* r = p;
        p += (bytes + 255) & ~(size_t)255;
        return r;
    };
    __bf16* xb = (__bf16*)nxt(8192ull * 1024 * 2);
    __bf16* WTqkg = (__bf16*)nxt(4096ull * 1024 * 2);  // WqT | WkT | WgT
    __bf16* WvT = (__bf16*)nxt(2048ull * 1024 * 2);
    __bf16* WoT = (__bf16*)nxt(1024ull * 2048 * 2);
    __bf16* qkg = (__bf16*)nxt(8192ull * 4096 * 2);
    __bf16* vt = (__bf16*)nxt(2048ull * 8192 * 2);
    float* tbuf = (float*)nxt(8192ull * 16 * 4);
    __bf16* qg = (__bf16*)nxt(8192ull * 1024 * 2);
    __bf16* kHt = (__bf16*)nxt(16ull * 256 * 2048 * 2);
    float* ebl = (float*)nxt(32ull * 16 * 256 * 4);
    __bf16* ob = (__bf16*)nxt(8192ull * 2048 * 2);
    __bf16* gated = (__bf16*)nxt(8192ull * 2048 * 2);

    dim3 tb(32, 8);
    cvt_bf16<<<8192, 256, 0, stream>>>(x, xb, 2097152);
    transpose_w<<<dim3(32, 32), tb, 0, stream>>>(Wq, WTqkg, 1024, 1024);
    transpose_w<<<dim3(32, 32), tb, 0, stream>>>(Wk, WTqkg + 1024 * 1024, 1024, 1024);
    transpose_w<<<dim3(64, 32), tb, 0, stream>>>(Wg, WTqkg + 2048 * 1024, 1024, 2048);
    transpose_w<<<dim3(64, 32), tb, 0, stream>>>(Wv, WvT, 1024, 2048);
    transpose_w<<<dim3(32, 64), tb, 0, stream>>>(Wo, WoT, 2048, 1024);
    gk1_proj<<<2048, 256, 0, stream>>>(x, w1, tbuf);
    gemm_bt<__bf16><<<2048, 256, 0, stream>>>(xb, WTqkg, qkg, 8192, 4096, 1024);
    gemm_bt<__bf16><<<1024, 256, 0, stream>>>(WvT, xb, vt, 2048, 8192, 1024);
    chunk_pre<<<512, 256, 0, stream>>>(tbuf, w2, b2, qkg, vt, qg, kHt, ebl, ob);
    scan_kernel<<<128, 512, 0, stream>>>(qg, kHt, vt, ebl, ob);
    rms_gate<<<8192, 256, 0, stream>>>(ob, qkg, gnw, gated);
    gemm_bt<float><<<512, 256, 0, stream>>>(gated, WoT, out, 8192, 1024, 2048);
}

// Round 3
// 541.396 us; speedup vs baseline: 1.0924x; 1.0924x over previous
//
#include <hip/hip_runtime.h>
#include <hip/hip_bf16.h>

typedef __attribute__((ext_vector_type(8))) __bf16 bf16x8;
typedef __attribute__((ext_vector_type(4))) __bf16 bf16x4;
typedef __attribute__((ext_vector_type(4))) float f32x4;

#define MFMA16(a, b, c) __builtin_amdgcn_mfma_f32_16x16x32_bf16((a), (b), (c), 0, 0, 0)

__device__ __forceinline__ void gload_lds16(const void* g, void* l) {
    __builtin_amdgcn_global_load_lds((const __attribute__((address_space(1))) void*)g,
                                     (__attribute__((address_space(3))) void*)l, 16, 0, 0);
}

// ---------------- f32 -> bf16 convert (x) ----------------
__global__ __launch_bounds__(256) void cvt_bf16(const float* __restrict__ in,
                                                __bf16* __restrict__ out, int n4) {
    int i = blockIdx.x * 256 + threadIdx.x;
    if (i >= n4) return;
    f32x4 v = *(const f32x4*)(in + (size_t)i * 4);
    bf16x4 o;
#pragma unroll
    for (int j = 0; j < 4; j++) o[j] = (__bf16)v[j];
    *(bf16x4*)(out + (size_t)i * 4) = o;
}

// ---------------- weight transpose f32 (R,C) -> bf16 (C,R) ----------------
__global__ __launch_bounds__(256) void transpose_w(const float* __restrict__ in,
                                                   __bf16* __restrict__ out, int R, int C) {
    __shared__ float tile[32][33];
    const int c0 = blockIdx.x * 32, r0 = blockIdx.y * 32;
    const int tx = threadIdx.x, ty = threadIdx.y;
#pragma unroll
    for (int k = 0; k < 32; k += 8)
        tile[ty + k][tx] = in[(size_t)(r0 + ty + k) * C + c0 + tx];
    __syncthreads();
#pragma unroll
    for (int k = 0; k < 32; k += 8)
        out[(size_t)(c0 + ty + k) * R + r0 + tx] = (__bf16)tile[tx][ty + k];
}

// ---------------- GEMM: C(M,N) = A(M,K)bf16 @ Bt(N,K)bf16^T  (m97 structure) ----------------
template <typename OUT_T>
__global__ __launch_bounds__(256) void gemm_bt(const __bf16* __restrict__ A,
                                               const __bf16* __restrict__ Bt,
                                               OUT_T* __restrict__ C, int M, int N, int K) {
    __shared__ alignas(16) __bf16 As[4096];
    __shared__ alignas(16) __bf16 Bs[4096];
    const int tid = threadIdx.x;
    const int wv = tid >> 6;
    const int nwg = gridDim.x;
    const int cpx = nwg >> 3;
    const int bid = blockIdx.x;
    const int wg = (bid & 7) * cpx + (bid >> 3);  // XCD swizzle (nwg % 8 == 0 in all launches)
    const int nbn = N >> 7;
    const int bm = wg / nbn, bn = wg - bm * nbn;

    const __bf16* Ab = A + (size_t)bm * 128 * K;
    const __bf16* Bb = Bt + (size_t)bn * 128 * K;
    const int srow = tid >> 2;
    const int skc = (tid & 3) * 8;
    const int lr = tid & 15;
    const int lk = ((tid >> 4) & 3) * 8;
    const int wm = (wv >> 1) * 64, wn = (wv & 1) * 64;

    f32x4 acc[4][4] = {};
    for (int kt = 0; kt < K; kt += 32) {
        gload_lds16(Ab + (size_t)srow * K + kt + skc, As + wv * 512);
        gload_lds16(Ab + (size_t)(srow + 64) * K + kt + skc, As + 2048 + wv * 512);
        gload_lds16(Bb + (size_t)srow * K + kt + skc, Bs + wv * 512);
        gload_lds16(Bb + (size_t)(srow + 64) * K + kt + skc, Bs + 2048 + wv * 512);
        asm volatile("s_waitcnt vmcnt(0)" ::: "memory");
        __syncthreads();
        bf16x8 af[4], bfr[4];
#pragma unroll
        for (int i = 0; i < 4; i++) af[i] = *(const bf16x8*)(As + (wm + i * 16 + lr) * 32 + lk);
#pragma unroll
        for (int j = 0; j < 4; j++) bfr[j] = *(const bf16x8*)(Bs + (wn + j * 16 + lr) * 32 + lk);
#pragma unroll
        for (int i = 0; i < 4; i++)
#pragma unroll
            for (int j = 0; j < 4; j++) acc[i][j] = MFMA16(af[i], bfr[j], acc[i][j]);
        __syncthreads();
    }
    const int lro = ((tid >> 4) & 3) * 4;
#pragma unroll
    for (int i = 0; i < 4; i++)
#pragma unroll
        for (int j = 0; j < 4; j++) {
            size_t base = (size_t)(bm * 128 + wm + i * 16 + lro) * N + bn * 128 + wn + j * 16 + lr;
#pragma unroll
            for (int r = 0; r < 4; r++) C[base + (size_t)r * N] = (OUT_T)acc[i][j][r];
        }
}

// ---------------- t = x @ gk_w1  (8192x16) ----------------
__global__ __launch_bounds__(256) void gk1_proj(const float* __restrict__ x,
                                                const float* __restrict__ w1,
                                                float* __restrict__ t) {
    const int row = blockIdx.x * 4 + (threadIdx.x >> 6);
    const int l = threadIdx.x & 63;
    const int r = l & 15, kg = l >> 4;
    const float* xr = x + (size_t)row * 1024;
    const float* w1p = w1 + r;
    float acc = 0.f;
    for (int k = kg * 256; k < (kg + 1) * 256; ++k) acc = fmaf(xr[k], w1p[k * 16], acc);
    acc += __shfl_xor(acc, 16);
    acc += __shfl_xor(acc, 32);
    if (kg == 0) t[(size_t)row * 16 + r] = acc;
}

// ---------------- per-(b,h,chunk128): gates, qg, kg, kgT, e^blast ----------------
__global__ __launch_bounds__(256) void gate_qkg(
    const float* __restrict__ tbuf,   // (8192,16)
    const float* __restrict__ w2,     // (16,1024)
    const float* __restrict__ b2,     // (1024)
    const __bf16* __restrict__ qkbuf, // (8192,2048): q|k
    __bf16* __restrict__ qg,          // (8192,1024)
    __bf16* __restrict__ kg,          // (8192,1024)
    __bf16* __restrict__ kgT,         // (16,256,2048) [bh][d][seq]
    float* __restrict__ ebl)          // (16,16,256) [nc][bh][d]
{
    __shared__ float t_l[128 * 16];
    __shared__ __bf16 kg_l[128 * 260];
    const int bid = blockIdx.x;
    const int bh = bid & 15, nc = bid >> 4;
    const int b = bh >> 2, h = bh & 3;
    const int tid = threadIdx.x;
    const int seq0 = b * 2048 + nc * 128;
    const int hd = h * 256 + tid;

    for (int i = tid; i < 128 * 16; i += 256) t_l[i] = tbuf[(size_t)seq0 * 16 + i];
    float w2c[16];
#pragma unroll
    for (int r = 0; r < 16; r++) w2c[r] = w2[r * 1024 + hd];
    const float b2v = b2[hd];
    __syncthreads();

    float bsum = 0.f;
    for (int c = 0; c < 128; c++) {
        float u = b2v;
#pragma unroll
        for (int r = 0; r < 16; r++) u += t_l[c * 16 + r] * w2c[r];
        float ls = fminf(u, 0.f) - log1pf(expf(-fabsf(u)));  // log_sigmoid
        bsum += ls * 0.0625f;                                // / GATE_NORM
        float qv = (float)qkbuf[(size_t)(seq0 + c) * 2048 + hd];
        float kv = (float)qkbuf[(size_t)(seq0 + c) * 2048 + 1024 + hd];
        qg[(size_t)(seq0 + c) * 1024 + hd] = (__bf16)(qv * expf(bsum) * 0.0625f);
        __bf16 kgv = (__bf16)(kv * expf(-bsum));
        kg[(size_t)(seq0 + c) * 1024 + hd] = kgv;
        kg_l[c * 260 + tid] = kgv;
    }
    ebl[(size_t)(nc * 16 + bh) * 256 + tid] = expf(bsum);
    __syncthreads();

    // transpose kg -> kgT (seq-contiguous rows per d)
    const int cc = tid & 127, half = tid >> 7;
    for (int i = 0; i < 128; i++) {
        int dd = half * 128 + i;
        kgT[(size_t)(bh * 256 + dd) * 2048 + nc * 128 + cc] = kg_l[cc * 260 + dd];
    }
}

// ---------------- intra: A = qg kg^T (128x128 causal), o_intra = A v (e-half) ----------------
// grid 512 = eh(2) x nc(16) x bh(16)
__global__ __launch_bounds__(512) void intra(
    const __bf16* __restrict__ qg, const __bf16* __restrict__ kg,
    const __bf16* __restrict__ vt, __bf16* __restrict__ ob) {
    __shared__ alignas(16) __bf16 A_l[128 * 128];  // XOR-swizzled
    const int bid = blockIdx.x;
    const int bh = bid & 15, jj = bid >> 4;
    const int nc = jj >> 1, eh = jj & 1;
    const int b = bh >> 2, h = bh & 3;
    const int tid = threadIdx.x, wv = tid >> 6, l = tid & 63;
    const int lr = l & 15, lk = (l >> 4) * 8, lro = (l >> 4) * 4;
    const int seq0 = b * 2048 + nc * 128;

    bf16x8 af[8];
    const __bf16* qrow = qg + (size_t)(seq0 + wv * 16 + lr) * 1024 + h * 256;
#pragma unroll
    for (int ks = 0; ks < 8; ks++) af[ks] = *(const bf16x8*)(qrow + ks * 32 + lk);
    for (int sj = 0; sj <= wv; sj++) {
        f32x4 acc = {};
#pragma unroll
        for (int ks = 0; ks < 8; ks++) {
            bf16x8 bb = *(const bf16x8*)(kg + (size_t)(seq0 + sj * 16 + lr) * 1024 + h * 256 + ks * 32 + lk);
            acc = MFMA16(af[ks], bb, acc);
        }
#pragma unroll
        for (int r = 0; r < 4; r++) {
            int t = wv * 16 + lro + r;
            int s = sj * 16 + lr;
            A_l[t * 128 + (s ^ ((t & 7) << 3))] = (s <= t) ? (__bf16)acc[r] : (__bf16)0.f;
        }
    }
    for (int sj = wv + 1; sj < 8; sj++)
#pragma unroll
        for (int r = 0; r < 4; r++) {
            int t = wv * 16 + lro + r;
            int s = sj * 16 + lr;
            A_l[t * 128 + (s ^ ((t & 7) << 3))] = (__bf16)0.f;
        }
    __syncthreads();

    f32x4 acc2[16] = {};
#pragma unroll
    for (int ks = 0; ks < 4; ks++) {
        int t = wv * 16 + lr;
        bf16x8 a = *(const bf16x8*)(A_l + t * 128 + ((ks * 32 + lk) ^ ((t & 7) << 3)));
#pragma unroll
        for (int cf = 0; cf < 16; cf++) {
            bf16x8 bb = *(const bf16x8*)(vt + (size_t)(h * 512 + eh * 256 + cf * 16 + lr) * 8192 + seq0 + ks * 32 + lk);
            acc2[cf] = MFMA16(a, bb, acc2[cf]);
        }
    }
#pragma unroll
    for (int cf = 0; cf < 16; cf++)
#pragma unroll
        for (int r = 0; r < 4; r++)
            ob[(size_t)(seq0 + wv * 16 + lro + r) * 2048 + h * 512 + eh * 256 + cf * 16 + lr] =
                (__bf16)acc2[cf][r];
}

// ---------------- sequential scan (C=128, 16 steps): o_int = qg H^T ; H = e^bl (H + kg^T v) ----------------
// grid 256 = es(16) x bh(16)
__global__ __launch_bounds__(512) void scan2(
    const __bf16* __restrict__ qg, const __bf16* __restrict__ kgT,
    const __bf16* __restrict__ vt, const float* __restrict__ ebl,
    __bf16* __restrict__ o_int) {
    __shared__ alignas(16) __bf16 Ht[32 * 256];  // [e][d] XOR-swizzled, 16KB
    const int bid = blockIdx.x;
    const int bh = bid & 15, es = bid >> 4;
    const int b = bh >> 2, h = bh & 3;
    const int tid = threadIdx.x, wv = tid >> 6, l = tid & 63;
    const int lr = l & 15, lk = (l >> 4) * 8, lro = (l >> 4) * 4;
    const int uw = wv - 4;
    const int ecol0 = h * 512 + es * 32;

    {
        bf16x8 z = {};
        for (int i = tid; i < 1024; i += 512) *(bf16x8*)(Ht + i * 8) = z;
    }
    __syncthreads();

    for (int nc = 0; nc < 16; nc++) {
        const int seq0 = b * 2048 + nc * 128;
        f32x4 accA[2][2] = {};
        f32x4 accU[2][4] = {};
        if (wv < 4) {
            // o_inter rows [wv*32, +32), cols [ecol0, +32), K = 256 (d)
#pragma unroll
            for (int ks = 0; ks < 8; ks++) {
                bf16x8 a[2];
#pragma unroll
                for (int i = 0; i < 2; i++)
                    a[i] = *(const bf16x8*)(qg + (size_t)(seq0 + wv * 32 + i * 16 + lr) * 1024 + h * 256 + ks * 32 + lk);
#pragma unroll
                for (int j = 0; j < 2; j++) {
                    int e = j * 16 + lr;
                    bf16x8 bb = *(const bf16x8*)(Ht + e * 256 + ((ks * 32 + lk) ^ ((e & 7) << 3)));
#pragma unroll
                    for (int i = 0; i < 2; i++) accA[i][j] = MFMA16(a[i], bb, accA[i][j]);
                }
            }
        } else {
            // U^T[e][d] = sum_c vt[e][c] kgT[d][c]; this wave: d in [uw*64, +64), e all 32
#pragma unroll
            for (int ks = 0; ks < 4; ks++) {
                bf16x8 a[2];
#pragma unroll
                for (int et = 0; et < 2; et++)
                    a[et] = *(const bf16x8*)(vt + (size_t)(ecol0 + et * 16 + lr) * 8192 + seq0 + ks * 32 + lk);
#pragma unroll
                for (int dt = 0; dt < 4; dt++) {
                    bf16x8 bb = *(const bf16x8*)(kgT + (size_t)(bh * 256 + uw * 64 + dt * 16 + lr) * 2048 + nc * 128 + ks * 32 + lk);
#pragma unroll
                    for (int et = 0; et < 2; et++) accU[et][dt] = MFMA16(a[et], bb, accU[et][dt]);
                }
            }
        }
        __syncthreads();  // (1) all Ht reads done, U ready
        if (wv < 4) {
#pragma unroll
            for (int i = 0; i < 2; i++)
#pragma unroll
                for (int j = 0; j < 2; j++)
#pragma unroll
                    for (int r = 0; r < 4; r++)
                        o_int[(size_t)(seq0 + wv * 32 + i * 16 + lro + r) * 2048 + ecol0 + j * 16 + lr] =
                            (__bf16)accA[i][j][r];
        } else {
            const float* ep = ebl + (size_t)(nc * 16 + bh) * 256;
#pragma unroll
            for (int dt = 0; dt < 4; dt++) {
                const int d = uw * 64 + dt * 16 + lr;
                const float e = ep[d];
#pragma unroll
                for (int et = 0; et < 2; et++)
#pragma unroll
                    for (int r = 0; r < 4; r++) {
                        int erow = et * 16 + lro + r;
                        int idx = erow * 256 + (d ^ ((erow & 7) << 3));
                        Ht[idx] = (__bf16)(e * ((float)Ht[idx] + accU[et][dt][r]));
                    }
            }
        }
        __syncthreads();  // (2) Ht updated
    }
}

// ---------------- RMS norm over dv=512 + SiLU gating (o = ob + o_int) ----------------
__global__ __launch_bounds__(256) void rms_gate(const __bf16* __restrict__ ob,
                                                const __bf16* __restrict__ o_int,
                                                const __bf16* __restrict__ gbuf,
                                                const float* __restrict__ gnw,
                                                __bf16* __restrict__ gated) {
    const int idx = blockIdx.x * 4 + (threadIdx.x >> 6);
    const int seq = idx >> 2, h = idx & 3;
    const int l = threadIdx.x & 63;
    bf16x8 o1 = *(const bf16x8*)(ob + (size_t)seq * 2048 + h * 512 + l * 8);
    bf16x8 o2 = *(const bf16x8*)(o_int + (size_t)seq * 2048 + h * 512 + l * 8);
    float v[8];
    float ms = 0.f;
#pragma unroll
    for (int j = 0; j < 8; j++) {
        v[j] = (float)o1[j] + (float)o2[j];
        ms += v[j] * v[j];
    }
#pragma unroll
    for (int off = 1; off < 64; off <<= 1) ms += __shfl_xor(ms, off);
    const float rinv = rsqrtf(ms * (1.f / 512.f) + 1e-5f);
    bf16x8 gv = *(const bf16x8*)(gbuf + (size_t)seq * 4096 / 2 + h * 512 + l * 8);
    const float* gw = gnw + l * 8;
    bf16x8 outv;
#pragma unroll
    for (int j = 0; j < 8; j++) {
        float g = (float)gv[j];
        float sig = 1.f / (1.f + expf(-g));
        outv[j] = (__bf16)(v[j] * rinv * gw[j] * g * sig);
    }
    *(bf16x8*)(gated + (size_t)seq * 2048 + h * 512 + l * 8) = outv;
}

extern "C" void kernel_launch(void* const* d_in, const int* in_sizes, int n_in,
                              void* d_out, int out_size, void* d_ws, size_t ws_size,
                              hipStream_t stream) {
    const float* x = (const float*)d_in[0];
    const float* Wq = (const float*)d_in[1];
    const float* Wk = (const float*)d_in[2];
    const float* Wv = (const float*)d_in[3];
    const float* Wg = (const float*)d_in[4];
    const float* w1 = (const float*)d_in[5];
    const float* w2 = (const float*)d_in[6];
    const float* b2 = (const float*)d_in[7];
    const float* gnw = (const float*)d_in[8];
    const float* Wo = (const float*)d_in[9];
    float* out = (float*)d_out;

    char* p = (char*)d_ws;
    auto nxt = [&](size_t bytes) {
        char* r = p;
        p += (bytes + 255) & ~(size_t)255;
        return r;
    };
    __bf16* xb = (__bf16*)nxt(8192ull * 1024 * 2);    // dead after vt GEMM -> kg aliases
    __bf16* WTqk = (__bf16*)nxt(2048ull * 1024 * 2);  // WqT | WkT
    __bf16* WTg = (__bf16*)nxt(2048ull * 1024 * 2);
    __bf16* WvT = (__bf16*)nxt(2048ull * 1024 * 2);
    __bf16* WoT = (__bf16*)nxt(1024ull * 2048 * 2);
    __bf16* qkbuf = (__bf16*)nxt(8192ull * 2048 * 2);  // dead after gate_qkg -> o_int aliases
    __bf16* gbuf = (__bf16*)nxt(8192ull * 2048 * 2);
    __bf16* vt = (__bf16*)nxt(2048ull * 8192 * 2);
    float* tbuf = (float*)nxt(8192ull * 16 * 4);
    __bf16* qg = (__bf16*)nxt(8192ull * 1024 * 2);
    __bf16* kgT = (__bf16*)nxt(16ull * 256 * 2048 * 2);
    float* ebl = (float*)nxt(16ull * 16 * 256 * 4);
    __bf16* ob = (__bf16*)nxt(8192ull * 2048 * 2);
    __bf16* gated = (__bf16*)nxt(8192ull * 2048 * 2);
    __bf16* kg = xb;       // alias: xb dead before gate_qkg writes kg
    __bf16* o_int = qkbuf; // alias: qkbuf dead before scan2 writes o_int

    dim3 tb(32, 8);
    cvt_bf16<<<8192, 256, 0, stream>>>(x, xb, 2097152);
    transpose_w<<<dim3(32, 32), tb, 0, stream>>>(Wq, WTqk, 1024, 1024);
    transpose_w<<<dim3(32, 32), tb, 0, stream>>>(Wk, WTqk + 1024 * 1024, 1024, 1024);
    transpose_w<<<dim3(64, 32), tb, 0, stream>>>(Wg, WTg, 1024, 2048);
    transpose_w<<<dim3(64, 32), tb, 0, stream>>>(Wv, WvT, 1024, 2048);
    transpose_w<<<dim3(32, 64), tb, 0, stream>>>(Wo, WoT, 2048, 1024);
    gk1_proj<<<2048, 256, 0, stream>>>(x, w1, tbuf);
    gemm_bt<__bf16><<<1024, 256, 0, stream>>>(xb, WTqk, qkbuf, 8192, 2048, 1024);
    gemm_bt<__bf16><<<1024, 256, 0, stream>>>(xb, WTg, gbuf, 8192, 2048, 1024);
    gemm_bt<__bf16><<<1024, 256, 0, stream>>>(WvT, xb, vt, 2048, 8192, 1024);
    gate_qkg<<<256, 256, 0, stream>>>(tbuf, w2, b2, qkbuf, qg, kg, kgT, ebl);
    intra<<<512, 512, 0, stream>>>(qg, kg, vt, ob);   // FIX: 512 blocks (was 256 -> chunks 8-15 missing)
    scan2<<<256, 512, 0, stream>>>(qg, kgT, vt, ebl, o_int);
    rms_gate<<<8192, 256, 0, stream>>>(ob, o_int, gbuf, gnw, gated);
    gemm_bt<float><<<512, 256, 0, stream>>>(gated, WoT, out, 8192, 1024, 2048);
}